// Round 1
// baseline (652.102 us; speedup 1.0000x reference)
//
#include <hip/hip_runtime.h>

#define T_TOK 4096
#define H_DIM 1024
#define I_DIM 2048
#define E_NUM 16
#define K_TOP 4
#define BM 128
#define BK 32
#define MAX_TILES 144
#define PAD_PAIRS (MAX_TILES * BM)  // 18432

typedef __attribute__((ext_vector_type(8))) short s16x8;
typedef __attribute__((ext_vector_type(4))) float f32x4;
typedef __attribute__((ext_vector_type(4))) unsigned short u16x4;

__device__ __forceinline__ unsigned short f2bf(float f) {
  unsigned u = __float_as_uint(f);
  u += 0x7fffu + ((u >> 16) & 1u);  // round-to-nearest-even
  return (unsigned short)(u >> 16);
}

__device__ __forceinline__ void mfma_bf16(const s16x8& a, const s16x8& b, f32x4& c) {
  asm("v_mfma_f32_16x16x32_bf16 %0, %1, %2, %0" : "+v"(c) : "v"(a), "v"(b));
}

__device__ __forceinline__ void gld16(const void* g, void* l) {
  __builtin_amdgcn_global_load_lds(
      (const __attribute__((address_space(1))) unsigned int*)g,
      (__attribute__((address_space(3))) unsigned int*)l, 16, 0, 0);
}

// ---------------- router: logits -> softmax top4 -> weights; also x -> bf16 ----
__global__ __launch_bounds__(256) void router_kernel(
    const float* __restrict__ x, const float* __restrict__ rw,
    const float* __restrict__ rb, int* __restrict__ topi,
    float* __restrict__ topw, int* __restrict__ counts,
    unsigned short* __restrict__ xb) {
  const int w = threadIdx.x >> 6, l = threadIdx.x & 63;
  const int t = blockIdx.x * 4 + w;
  const float* xrow = x + (size_t)t * H_DIM;
  unsigned short* xbrow = xb + (size_t)t * H_DIM;
  float p[E_NUM];
#pragma unroll
  for (int e = 0; e < E_NUM; ++e) p[e] = 0.f;
  for (int h = l; h < H_DIM; h += 64) {
    float xv = xrow[h];
    xbrow[h] = f2bf(xv);
    const f32x4* rwp = (const f32x4*)(rw + (size_t)h * E_NUM);
#pragma unroll
    for (int q = 0; q < 4; ++q) {
      f32x4 r = rwp[q];
      p[q * 4 + 0] += xv * r[0];
      p[q * 4 + 1] += xv * r[1];
      p[q * 4 + 2] += xv * r[2];
      p[q * 4 + 3] += xv * r[3];
    }
  }
#pragma unroll
  for (int e = 0; e < E_NUM; ++e) {
#pragma unroll
    for (int off = 32; off; off >>= 1) p[e] += __shfl_xor(p[e], off, 64);
  }
  if (l == 0) {
    float mx = -1e30f;
#pragma unroll
    for (int e = 0; e < E_NUM; ++e) { p[e] += rb[e]; mx = fmaxf(mx, p[e]); }
    float ex[E_NUM];
#pragma unroll
    for (int e = 0; e < E_NUM; ++e) ex[e] = expf(p[e] - mx);
    unsigned used = 0;
    int isel[K_TOP];
    float wsel[K_TOP], subs = 0.f;
#pragma unroll
    for (int k = 0; k < K_TOP; ++k) {
      int bi = 0;
      float bv = -1.f;
      for (int e = 0; e < E_NUM; ++e) {
        if (!((used >> e) & 1u) && ex[e] > bv) { bv = ex[e]; bi = e; }
      }
      used |= 1u << bi;
      isel[k] = bi; wsel[k] = bv; subs += bv;
    }
    float inv = 1.f / subs;
#pragma unroll
    for (int k = 0; k < K_TOP; ++k) {
      topi[t * K_TOP + k] = isel[k];
      topw[t * K_TOP + k] = wsel[k] * inv;
      atomicAdd(&counts[isel[k]], 1);
    }
  }
}

// ---------------- scan: padded offsets + static tile map -----------------------
__global__ void scan_kernel(const int* __restrict__ counts, int* padBase,
                            int* tileExpert, int* tileStart, int* nTiles,
                            int* cursor) {
  if (threadIdx.x != 0 || blockIdx.x != 0) return;
  int base = 0, nt = 0;
  for (int e = 0; e < E_NUM; ++e) {
    padBase[e] = base;
    cursor[e] = 0;
    int tc = (counts[e] + BM - 1) >> 7;
    for (int i = 0; i < tc; ++i) {
      tileExpert[nt] = e;
      tileStart[nt] = base + (i << 7);
      ++nt;
    }
    base += tc << 7;
  }
  nTiles[0] = nt;
}

// ---------------- scatter pairs into per-expert sorted order ------------------
__global__ __launch_bounds__(256) void scatter_kernel(
    const int* __restrict__ topi, const float* __restrict__ topw,
    const int* __restrict__ padBase, int* __restrict__ cursor,
    int* __restrict__ pairTok, float* __restrict__ pairW) {
  int t = blockIdx.x * 256 + threadIdx.x;
  if (t >= T_TOK) return;
#pragma unroll
  for (int k = 0; k < K_TOP; ++k) {
    int e = topi[t * K_TOP + k];
    int pos = atomicAdd(&cursor[e], 1);
    int idx = padBase[e] + pos;
    pairTok[idx] = t;
    pairW[idx] = topw[t * K_TOP + k];
  }
}

// ---------------- transpose f32 [R][C] -> bf16 [C][R] per expert (z) ----------
__global__ __launch_bounds__(256) void transpose_kernel(
    const float* __restrict__ src, unsigned short* __restrict__ dst, int R,
    int C) {
  size_t es = (size_t)R * C;
  src += es * blockIdx.z;
  dst += es * blockIdx.z;
  int r0 = blockIdx.y * 64, c0 = blockIdx.x * 64;
  __shared__ float tle[64][65];
  int rr = threadIdx.x >> 4, cc = (threadIdx.x & 15) * 4;
#pragma unroll
  for (int i = 0; i < 4; ++i) {
    f32x4 v = *(const f32x4*)(src + (size_t)(r0 + rr + 16 * i) * C + c0 + cc);
    tle[rr + 16 * i][cc + 0] = v[0];
    tle[rr + 16 * i][cc + 1] = v[1];
    tle[rr + 16 * i][cc + 2] = v[2];
    tle[rr + 16 * i][cc + 3] = v[3];
  }
  __syncthreads();
#pragma unroll
  for (int i = 0; i < 4; ++i) {
    int oc = c0 + rr + 16 * i;
    u16x4 o;
    o[0] = f2bf(tle[cc + 0][rr + 16 * i]);
    o[1] = f2bf(tle[cc + 1][rr + 16 * i]);
    o[2] = f2bf(tle[cc + 2][rr + 16 * i]);
    o[3] = f2bf(tle[cc + 3][rr + 16 * i]);
    *(u16x4*)(dst + (size_t)oc * R + r0 + cc) = o;
  }
}

// ---------------- grouped GEMM1: hmid = gelu(x[pairs] @ w1 + b1) --------------
__global__ __launch_bounds__(256) void gemm1_kernel(
    const unsigned short* __restrict__ xb, const unsigned short* __restrict__ w1t,
    const float* __restrict__ b1, unsigned short* __restrict__ hmid,
    const int* __restrict__ pairTok, const int* __restrict__ tileExpert,
    const int* __restrict__ tileStart, const int* __restrict__ nTiles) {
  const int mt = blockIdx.y;
  if (mt >= nTiles[0]) return;
  const int e = tileExpert[mt];
  const int tsp = tileStart[mt];
  const int n0 = blockIdx.x * 128;
  __shared__ unsigned short As[2][BM * BK];
  __shared__ unsigned short Bs[2][BM * BK];
  const int tid = threadIdx.x, w = tid >> 6, l = tid & 63;
  const int rbase = w * 16 + (l >> 2), seg = l & 3;
  int tok0 = pairTok[tsp + rbase];
  if (tok0 < 0) tok0 = 0;
  int tok1 = pairTok[tsp + rbase + 64];
  if (tok1 < 0) tok1 = 0;
  const char* gA0 = (const char*)(xb + (size_t)tok0 * H_DIM) + seg * 16;
  const char* gA1 = (const char*)(xb + (size_t)tok1 * H_DIM) + seg * 16;
  const unsigned short* wbase = w1t + (size_t)e * I_DIM * H_DIM;
  const char* gB0 = (const char*)(wbase + (size_t)(n0 + rbase) * H_DIM) + seg * 16;
  const char* gB1 = (const char*)(wbase + (size_t)(n0 + rbase + 64) * H_DIM) + seg * 16;

  f32x4 acc[4][4];
#pragma unroll
  for (int m = 0; m < 4; ++m)
#pragma unroll
    for (int n = 0; n < 4; ++n) acc[m][n] = f32x4{0.f, 0.f, 0.f, 0.f};

  const int wr = w >> 1, wc = w & 1, lrow = l & 15, g = l >> 4;
  const int NK = H_DIM / BK;  // 32

  gld16(gA0, &As[0][w * 512]);
  gld16(gA1, &As[0][2048 + w * 512]);
  gld16(gB0, &Bs[0][w * 512]);
  gld16(gB1, &Bs[0][2048 + w * 512]);

  for (int kt = 0; kt < NK; ++kt) {
    __syncthreads();
    if (kt + 1 < NK) {
      const int kb = (kt + 1) * 64;
      const int nb = (kt + 1) & 1;
      gld16(gA0 + kb, &As[nb][w * 512]);
      gld16(gA1 + kb, &As[nb][2048 + w * 512]);
      gld16(gB0 + kb, &Bs[nb][w * 512]);
      gld16(gB1 + kb, &Bs[nb][2048 + w * 512]);
    }
    const int cb = kt & 1;
    const s16x8* Ap = (const s16x8*)As[cb];
    const s16x8* Bp = (const s16x8*)Bs[cb];
    s16x8 av[4], bv[4];
#pragma unroll
    for (int m = 0; m < 4; ++m) av[m] = Ap[(wr * 64 + m * 16 + lrow) * 4 + g];
#pragma unroll
    for (int n = 0; n < 4; ++n) bv[n] = Bp[(wc * 64 + n * 16 + lrow) * 4 + g];
#pragma unroll
    for (int m = 0; m < 4; ++m)
#pragma unroll
      for (int n = 0; n < 4; ++n) mfma_bf16(av[m], bv[n], acc[m][n]);
  }

  const float* b1e = b1 + (size_t)e * I_DIM;
#pragma unroll
  for (int m = 0; m < 4; ++m) {
    const int rw0 = wr * 64 + m * 16 + g * 4;
#pragma unroll
    for (int n = 0; n < 4; ++n) {
      const int col = n0 + wc * 64 + n * 16 + lrow;
      const float bb = b1e[col];
      f32x4 v = acc[m][n];
#pragma unroll
      for (int j = 0; j < 4; ++j) {
        const int p = tsp + rw0 + j;
        float xv = v[j] + bb;
        float ge = 0.5f * xv * (1.f + erff(xv * 0.7071067811865476f));
        hmid[(size_t)p * I_DIM + col] = f2bf(ge);
      }
    }
  }
}

// ---------------- grouped GEMM2: out += ((hmid @ w2) + b2) * pairW ------------
__global__ __launch_bounds__(256) void gemm2_kernel(
    const unsigned short* __restrict__ hmid,
    const unsigned short* __restrict__ w2t, const float* __restrict__ b2,
    float* __restrict__ out, const int* __restrict__ pairTok,
    const float* __restrict__ pairW, const int* __restrict__ tileExpert,
    const int* __restrict__ tileStart, const int* __restrict__ nTiles) {
  const int mt = blockIdx.y;
  if (mt >= nTiles[0]) return;
  const int e = tileExpert[mt];
  const int tsp = tileStart[mt];
  const int n0 = blockIdx.x * 128;
  __shared__ unsigned short As[2][BM * BK];
  __shared__ unsigned short Bs[2][BM * BK];
  const int tid = threadIdx.x, w = tid >> 6, l = tid & 63;
  const int rbase = w * 16 + (l >> 2), seg = l & 3;
  const char* gA0 = (const char*)(hmid + (size_t)(tsp + rbase) * I_DIM) + seg * 16;
  const char* gA1 = (const char*)(hmid + (size_t)(tsp + rbase + 64) * I_DIM) + seg * 16;
  const unsigned short* wbase = w2t + (size_t)e * H_DIM * I_DIM;
  const char* gB0 = (const char*)(wbase + (size_t)(n0 + rbase) * I_DIM) + seg * 16;
  const char* gB1 = (const char*)(wbase + (size_t)(n0 + rbase + 64) * I_DIM) + seg * 16;

  f32x4 acc[4][4];
#pragma unroll
  for (int m = 0; m < 4; ++m)
#pragma unroll
    for (int n = 0; n < 4; ++n) acc[m][n] = f32x4{0.f, 0.f, 0.f, 0.f};

  const int wr = w >> 1, wc = w & 1, lrow = l & 15, g = l >> 4;
  const int NK = I_DIM / BK;  // 64

  gld16(gA0, &As[0][w * 512]);
  gld16(gA1, &As[0][2048 + w * 512]);
  gld16(gB0, &Bs[0][w * 512]);
  gld16(gB1, &Bs[0][2048 + w * 512]);

  for (int kt = 0; kt < NK; ++kt) {
    __syncthreads();
    if (kt + 1 < NK) {
      const int kb = (kt + 1) * 64;
      const int nb = (kt + 1) & 1;
      gld16(gA0 + kb, &As[nb][w * 512]);
      gld16(gA1 + kb, &As[nb][2048 + w * 512]);
      gld16(gB0 + kb, &Bs[nb][w * 512]);
      gld16(gB1 + kb, &Bs[nb][2048 + w * 512]);
    }
    const int cb = kt & 1;
    const s16x8* Ap = (const s16x8*)As[cb];
    const s16x8* Bp = (const s16x8*)Bs[cb];
    s16x8 av[4], bv[4];
#pragma unroll
    for (int m = 0; m < 4; ++m) av[m] = Ap[(wr * 64 + m * 16 + lrow) * 4 + g];
#pragma unroll
    for (int n = 0; n < 4; ++n) bv[n] = Bp[(wc * 64 + n * 16 + lrow) * 4 + g];
#pragma unroll
    for (int m = 0; m < 4; ++m)
#pragma unroll
      for (int n = 0; n < 4; ++n) mfma_bf16(av[m], bv[n], acc[m][n]);
  }

  const float* b2e = b2 + (size_t)e * H_DIM;
#pragma unroll
  for (int m = 0; m < 4; ++m) {
    const int rw0 = wr * 64 + m * 16 + g * 4;
#pragma unroll
    for (int j = 0; j < 4; ++j) {
      const int p = tsp + rw0 + j;
      const int tok = pairTok[p];
      if (tok < 0) continue;
      const float pw = pairW[p];
      float* orow = out + (size_t)tok * H_DIM;
#pragma unroll
      for (int n = 0; n < 4; ++n) {
        const int col = n0 + wc * 64 + n * 16 + lrow;
        float val = (acc[m][n][j] + b2e[col]) * pw;
        atomicAdd(orow + col, val);
      }
    }
  }
}

// ------------------------------------------------------------------------------
extern "C" void kernel_launch(void* const* d_in, const int* in_sizes, int n_in,
                              void* d_out, int out_size, void* d_ws,
                              size_t ws_size, hipStream_t stream) {
  const float* x = (const float*)d_in[0];
  const float* rw = (const float*)d_in[1];
  const float* rb = (const float*)d_in[2];
  const float* w1 = (const float*)d_in[3];
  const float* b1 = (const float*)d_in[4];
  const float* w2 = (const float*)d_in[5];
  const float* b2 = (const float*)d_in[6];
  float* out = (float*)d_out;
  char* ws = (char*)d_ws;

  size_t off = 0;
  unsigned short* xb = (unsigned short*)(ws + off);
  off += (size_t)T_TOK * H_DIM * 2;  // 8.39 MB
  unsigned short* wT = (unsigned short*)(ws + off);
  off += (size_t)E_NUM * H_DIM * I_DIM * 2;  // 67.1 MB (shared by w1T then w2T)
  unsigned short* hmid = (unsigned short*)(ws + off);
  off += (size_t)PAD_PAIRS * I_DIM * 2;  // 75.5 MB
  int* topi = (int*)(ws + off);      off += (size_t)T_TOK * K_TOP * 4;
  float* topw = (float*)(ws + off);  off += (size_t)T_TOK * K_TOP * 4;
  int* pairTok = (int*)(ws + off);   off += (size_t)PAD_PAIRS * 4;
  float* pairW = (float*)(ws + off); off += (size_t)PAD_PAIRS * 4;
  int* counts = (int*)(ws + off);    off += 64;
  int* cursor = (int*)(ws + off);    off += 64;
  int* padBase = (int*)(ws + off);   off += 64;
  int* tileExpert = (int*)(ws + off); off += MAX_TILES * 4;
  int* tileStart = (int*)(ws + off);  off += MAX_TILES * 4;
  int* nTiles = (int*)(ws + off);     off += 64;

  if (ws_size < off) return;  // ws too small -> output stays 0 (diagnostic)

  hipMemsetAsync(counts, 0, 64, stream);
  hipMemsetAsync(pairTok, 0xFF, (size_t)PAD_PAIRS * 4, stream);
  hipMemsetAsync(out, 0, (size_t)T_TOK * H_DIM * 4, stream);

  router_kernel<<<T_TOK / 4, 256, 0, stream>>>(x, rw, rb, topi, topw, counts, xb);
  scan_kernel<<<1, 64, 0, stream>>>(counts, padBase, tileExpert, tileStart,
                                    nTiles, cursor);
  scatter_kernel<<<T_TOK / 256, 256, 0, stream>>>(topi, topw, padBase, cursor,
                                                  pairTok, pairW);
  transpose_kernel<<<dim3(I_DIM / 64, H_DIM / 64, E_NUM), 256, 0, stream>>>(
      w1, wT, H_DIM, I_DIM);
  gemm1_kernel<<<dim3(I_DIM / 128, MAX_TILES), 256, 0, stream>>>(
      xb, wT, b1, hmid, pairTok, tileExpert, tileStart, nTiles);
  transpose_kernel<<<dim3(H_DIM / 64, I_DIM / 64, E_NUM), 256, 0, stream>>>(
      w2, wT, I_DIM, H_DIM);
  gemm2_kernel<<<dim3(H_DIM / 128, MAX_TILES), 256, 0, stream>>>(
      hmid, wT, b2, out, pairTok, pairW, tileExpert, tileStart, nTiles);
}

// Round 2
// 494.455 us; speedup vs baseline: 1.3188x; 1.3188x over previous
//
#include <hip/hip_runtime.h>

#define T_TOK 4096
#define H_DIM 1024
#define I_DIM 2048
#define E_NUM 16
#define K_TOP 4
#define BM 128
#define BK 32
#define MAX_TILES 144
#define PAD_PAIRS (MAX_TILES * BM)  // 18432
#define RW_Q 4104                   // padded quarter stride (words) for router rw LDS

typedef __attribute__((ext_vector_type(8))) short s16x8;
typedef __attribute__((ext_vector_type(4))) float f32x4;
typedef __attribute__((ext_vector_type(4))) unsigned short u16x4;
typedef __attribute__((ext_vector_type(8))) unsigned short u16x8;

__device__ __forceinline__ unsigned short f2bf(float f) {
  unsigned u = __float_as_uint(f);
  u += 0x7fffu + ((u >> 16) & 1u);  // round-to-nearest-even
  return (unsigned short)(u >> 16);
}

__device__ __forceinline__ void mfma_bf16(const s16x8& a, const s16x8& b, f32x4& c) {
  asm("v_mfma_f32_16x16x32_bf16 %0, %1, %2, %0" : "+v"(c) : "v"(a), "v"(b));
}

__device__ __forceinline__ void gld16(const void* g, void* l) {
  __builtin_amdgcn_global_load_lds(
      (const __attribute__((address_space(1))) unsigned int*)g,
      (__attribute__((address_space(3))) unsigned int*)l, 16, 0, 0);
}

// ---------------- x -> bf16 (vectorized elementwise) --------------------------
__global__ __launch_bounds__(256) void cvt_kernel(const float* __restrict__ x,
                                                  unsigned short* __restrict__ xb) {
  size_t i = ((size_t)blockIdx.x * 256 + threadIdx.x) * 8;
  f32x4 a = *(const f32x4*)(x + i);
  f32x4 b = *(const f32x4*)(x + i + 4);
  u16x8 o;
  o[0] = f2bf(a[0]); o[1] = f2bf(a[1]); o[2] = f2bf(a[2]); o[3] = f2bf(a[3]);
  o[4] = f2bf(b[0]); o[5] = f2bf(b[1]); o[6] = f2bf(b[2]); o[7] = f2bf(b[3]);
  *(u16x8*)(xb + i) = o;
}

// ---------------- router: lane = (expert, quarter), rw in padded LDS ----------
__global__ __launch_bounds__(256) void router_kernel(
    const float* __restrict__ x, const float* __restrict__ rw,
    const float* __restrict__ rb, int* __restrict__ topi,
    float* __restrict__ topw, int* __restrict__ counts) {
  __shared__ float rws[4 * RW_Q];  // ~65.7 KB
  const int tid = threadIdx.x;
  for (int idx = tid * 4; idx < H_DIM * E_NUM; idx += 256 * 4) {
    f32x4 v = *(const f32x4*)(rw + idx);
    int h = idx >> 4, e0 = idx & 15;
    *(f32x4*)&rws[(h >> 8) * RW_Q + (h & 255) * 16 + e0] = v;
  }
  __syncthreads();
  const int w = tid >> 6, l = tid & 63;
  const int e = l & 15, q = l >> 4;
  const float rbe = rb[e];
  const float* ldsb = &rws[q * RW_Q + e];
#pragma unroll
  for (int i = 0; i < 4; ++i) {
    const int t = blockIdx.x * 16 + w * 4 + i;
    const float* xr = x + (size_t)t * H_DIM + (q << 8);
    float acc = 0.f;
#pragma unroll 8
    for (int hh = 0; hh < 256; hh += 4) {
      f32x4 xv = *(const f32x4*)(xr + hh);
      acc += xv[0] * ldsb[(hh + 0) * 16];
      acc += xv[1] * ldsb[(hh + 1) * 16];
      acc += xv[2] * ldsb[(hh + 2) * 16];
      acc += xv[3] * ldsb[(hh + 3) * 16];
    }
    acc += __shfl_xor(acc, 16);
    acc += __shfl_xor(acc, 32);
    float logit = acc + rbe;
    float m = logit;
    m = fmaxf(m, __shfl_xor(m, 1));
    m = fmaxf(m, __shfl_xor(m, 2));
    m = fmaxf(m, __shfl_xor(m, 4));
    m = fmaxf(m, __shfl_xor(m, 8));
    float ex = expf(logit - m);
    int rank = 0;
    const int b16 = l & 48;
#pragma unroll
    for (int j = 0; j < 16; ++j) {
      float vj = __shfl(ex, b16 + j);
      rank += (vj > ex) || (vj == ex && j < e);
    }
    float sel = (rank < K_TOP) ? ex : 0.f;
    float subs = sel;
    subs += __shfl_xor(subs, 1);
    subs += __shfl_xor(subs, 2);
    subs += __shfl_xor(subs, 4);
    subs += __shfl_xor(subs, 8);
    if (q == 0 && rank < K_TOP) {
      topi[t * K_TOP + rank] = e;
      topw[t * K_TOP + rank] = ex / subs;
      atomicAdd(&counts[e], 1);
    }
  }
}

// ---------------- scan: padded offsets + static tile map -----------------------
__global__ void scan_kernel(const int* __restrict__ counts, int* padBase,
                            int* tileExpert, int* tileStart, int* nTiles,
                            int* cursor) {
  if (threadIdx.x != 0 || blockIdx.x != 0) return;
  int base = 0, nt = 0;
  for (int e = 0; e < E_NUM; ++e) {
    padBase[e] = base;
    cursor[e] = 0;
    int tc = (counts[e] + BM - 1) >> 7;
    for (int i = 0; i < tc; ++i) {
      tileExpert[nt] = e;
      tileStart[nt] = base + (i << 7);
      ++nt;
    }
    base += tc << 7;
  }
  nTiles[0] = nt;
}

// ---------------- scatter pairs into per-expert sorted order ------------------
__global__ __launch_bounds__(256) void scatter_kernel(
    const int* __restrict__ topi, const float* __restrict__ topw,
    const int* __restrict__ padBase, int* __restrict__ cursor,
    int* __restrict__ pairTok, float* __restrict__ pairW) {
  int t = blockIdx.x * 256 + threadIdx.x;
  if (t >= T_TOK) return;
#pragma unroll
  for (int k = 0; k < K_TOP; ++k) {
    int e = topi[t * K_TOP + k];
    int pos = atomicAdd(&cursor[e], 1);
    int idx = padBase[e] + pos;
    pairTok[idx] = t;
    pairW[idx] = topw[t * K_TOP + k];
  }
}

// ---------------- transpose f32 [R][C] -> bf16 [C][R] per expert (z) ----------
__global__ __launch_bounds__(256) void transpose_kernel(
    const float* __restrict__ src, unsigned short* __restrict__ dst, int R,
    int C) {
  size_t es = (size_t)R * C;
  src += es * blockIdx.z;
  dst += es * blockIdx.z;
  int r0 = blockIdx.y * 64, c0 = blockIdx.x * 64;
  __shared__ float tle[64][65];
  int rr = threadIdx.x >> 4, cc = (threadIdx.x & 15) * 4;
#pragma unroll
  for (int i = 0; i < 4; ++i) {
    f32x4 v = *(const f32x4*)(src + (size_t)(r0 + rr + 16 * i) * C + c0 + cc);
    tle[rr + 16 * i][cc + 0] = v[0];
    tle[rr + 16 * i][cc + 1] = v[1];
    tle[rr + 16 * i][cc + 2] = v[2];
    tle[rr + 16 * i][cc + 3] = v[3];
  }
  __syncthreads();
#pragma unroll
  for (int i = 0; i < 4; ++i) {
    int oc = c0 + rr + 16 * i;
    u16x4 o;
    o[0] = f2bf(tle[cc + 0][rr + 16 * i]);
    o[1] = f2bf(tle[cc + 1][rr + 16 * i]);
    o[2] = f2bf(tle[cc + 2][rr + 16 * i]);
    o[3] = f2bf(tle[cc + 3][rr + 16 * i]);
    *(u16x4*)(dst + (size_t)oc * R + r0 + cc) = o;
  }
}

// ---------------- grouped GEMM1: hmid = gelu(x[pairs] @ w1 + b1) --------------
// LDS XOR swizzle: LDS[row][c] = G[row][c ^ s(row)], s(row)=(row>>1)&3.
// Stage: lane(row=w*16+(l>>2), seg=l&3) sources chunk seg^((l>>3)&3).
// Read: lane(lrow=l&15, g=l>>4) reads chunk g^((l>>1)&3).
__global__ __launch_bounds__(256) void gemm1_kernel(
    const unsigned short* __restrict__ xb, const unsigned short* __restrict__ w1t,
    const float* __restrict__ b1, unsigned short* __restrict__ hmid,
    const int* __restrict__ pairTok, const int* __restrict__ tileExpert,
    const int* __restrict__ tileStart, const int* __restrict__ nTiles) {
  const int bid = blockIdx.x;
  const int lin = (bid & 7) * ((16 * MAX_TILES) >> 3) + (bid >> 3);  // XCD chunk
  const int tx = lin & 15, ty = lin >> 4;
  if (ty >= nTiles[0]) return;
  const int e = tileExpert[ty];
  const int tsp = tileStart[ty];
  const int n0 = tx * 128;
  __shared__ unsigned short As[2][BM * BK];
  __shared__ unsigned short Bs[2][BM * BK];
  const int tid = threadIdx.x, w = tid >> 6, l = tid & 63;
  const int rbase = w * 16 + (l >> 2);
  const int segp = (l & 3) ^ ((l >> 3) & 3);  // swizzled source chunk
  int tok0 = pairTok[tsp + rbase];
  if (tok0 < 0) tok0 = 0;
  int tok1 = pairTok[tsp + rbase + 64];
  if (tok1 < 0) tok1 = 0;
  const char* gA0 = (const char*)(xb + (size_t)tok0 * H_DIM) + segp * 16;
  const char* gA1 = (const char*)(xb + (size_t)tok1 * H_DIM) + segp * 16;
  const unsigned short* wbase = w1t + (size_t)e * I_DIM * H_DIM;
  const char* gB0 = (const char*)(wbase + (size_t)(n0 + rbase) * H_DIM) + segp * 16;
  const char* gB1 = (const char*)(wbase + (size_t)(n0 + rbase + 64) * H_DIM) + segp * 16;

  f32x4 acc[4][4];
#pragma unroll
  for (int m = 0; m < 4; ++m)
#pragma unroll
    for (int n = 0; n < 4; ++n) acc[m][n] = f32x4{0.f, 0.f, 0.f, 0.f};

  const int wr = w >> 1, wc = w & 1, lrow = l & 15, g = l >> 4;
  const int gs = g ^ ((l >> 1) & 3);  // swizzled read chunk
  const int NK = H_DIM / BK;  // 32

  gld16(gA0, &As[0][w * 512]);
  gld16(gA1, &As[0][2048 + w * 512]);
  gld16(gB0, &Bs[0][w * 512]);
  gld16(gB1, &Bs[0][2048 + w * 512]);

  for (int kt = 0; kt < NK; ++kt) {
    __syncthreads();
    if (kt + 1 < NK) {
      const int kb = (kt + 1) * 64;
      const int nb = (kt + 1) & 1;
      gld16(gA0 + kb, &As[nb][w * 512]);
      gld16(gA1 + kb, &As[nb][2048 + w * 512]);
      gld16(gB0 + kb, &Bs[nb][w * 512]);
      gld16(gB1 + kb, &Bs[nb][2048 + w * 512]);
    }
    const int cb = kt & 1;
    const s16x8* Ap = (const s16x8*)As[cb];
    const s16x8* Bp = (const s16x8*)Bs[cb];
    s16x8 av[4], bv[4];
#pragma unroll
    for (int m = 0; m < 4; ++m) av[m] = Ap[(wr * 64 + m * 16 + lrow) * 4 + gs];
#pragma unroll
    for (int n = 0; n < 4; ++n) bv[n] = Bp[(wc * 64 + n * 16 + lrow) * 4 + gs];
#pragma unroll
    for (int m = 0; m < 4; ++m)
#pragma unroll
      for (int n = 0; n < 4; ++n) mfma_bf16(av[m], bv[n], acc[m][n]);
  }

  const float* b1e = b1 + (size_t)e * I_DIM;
#pragma unroll
  for (int m = 0; m < 4; ++m) {
    const int rw0 = wr * 64 + m * 16 + g * 4;
#pragma unroll
    for (int n = 0; n < 4; ++n) {
      const int col = n0 + wc * 64 + n * 16 + lrow;
      const float bb = b1e[col];
      f32x4 v = acc[m][n];
#pragma unroll
      for (int j = 0; j < 4; ++j) {
        const int p = tsp + rw0 + j;
        float xv = v[j] + bb;
        float ge = 0.5f * xv * (1.f + erff(xv * 0.7071067811865476f));
        hmid[(size_t)p * I_DIM + col] = f2bf(ge);
      }
    }
  }
}

// ---------------- grouped GEMM2: out += ((hmid @ w2) + b2) * pairW ------------
__global__ __launch_bounds__(256) void gemm2_kernel(
    const unsigned short* __restrict__ hmid,
    const unsigned short* __restrict__ w2t, const float* __restrict__ b2,
    float* __restrict__ out, const int* __restrict__ pairTok,
    const float* __restrict__ pairW, const int* __restrict__ tileExpert,
    const int* __restrict__ tileStart, const int* __restrict__ nTiles) {
  const int bid = blockIdx.x;
  const int lin = (bid & 7) * ((8 * MAX_TILES) >> 3) + (bid >> 3);  // XCD chunk
  const int tx = lin & 7, ty = lin >> 3;
  if (ty >= nTiles[0]) return;
  const int e = tileExpert[ty];
  const int tsp = tileStart[ty];
  const int n0 = tx * 128;
  __shared__ unsigned short As[2][BM * BK];
  __shared__ unsigned short Bs[2][BM * BK];
  const int tid = threadIdx.x, w = tid >> 6, l = tid & 63;
  const int rbase = w * 16 + (l >> 2);
  const int segp = (l & 3) ^ ((l >> 3) & 3);
  const char* gA0 = (const char*)(hmid + (size_t)(tsp + rbase) * I_DIM) + segp * 16;
  const char* gA1 = (const char*)(hmid + (size_t)(tsp + rbase + 64) * I_DIM) + segp * 16;
  const unsigned short* wbase = w2t + (size_t)e * H_DIM * I_DIM;
  const char* gB0 = (const char*)(wbase + (size_t)(n0 + rbase) * I_DIM) + segp * 16;
  const char* gB1 = (const char*)(wbase + (size_t)(n0 + rbase + 64) * I_DIM) + segp * 16;

  f32x4 acc[4][4];
#pragma unroll
  for (int m = 0; m < 4; ++m)
#pragma unroll
    for (int n = 0; n < 4; ++n) acc[m][n] = f32x4{0.f, 0.f, 0.f, 0.f};

  const int wr = w >> 1, wc = w & 1, lrow = l & 15, g = l >> 4;
  const int gs = g ^ ((l >> 1) & 3);
  const int NK = I_DIM / BK;  // 64

  gld16(gA0, &As[0][w * 512]);
  gld16(gA1, &As[0][2048 + w * 512]);
  gld16(gB0, &Bs[0][w * 512]);
  gld16(gB1, &Bs[0][2048 + w * 512]);

  for (int kt = 0; kt < NK; ++kt) {
    __syncthreads();
    if (kt + 1 < NK) {
      const int kb = (kt + 1) * 64;
      const int nb = (kt + 1) & 1;
      gld16(gA0 + kb, &As[nb][w * 512]);
      gld16(gA1 + kb, &As[nb][2048 + w * 512]);
      gld16(gB0 + kb, &Bs[nb][w * 512]);
      gld16(gB1 + kb, &Bs[nb][2048 + w * 512]);
    }
    const int cb = kt & 1;
    const s16x8* Ap = (const s16x8*)As[cb];
    const s16x8* Bp = (const s16x8*)Bs[cb];
    s16x8 av[4], bv[4];
#pragma unroll
    for (int m = 0; m < 4; ++m) av[m] = Ap[(wr * 64 + m * 16 + lrow) * 4 + gs];
#pragma unroll
    for (int n = 0; n < 4; ++n) bv[n] = Bp[(wc * 64 + n * 16 + lrow) * 4 + gs];
#pragma unroll
    for (int m = 0; m < 4; ++m)
#pragma unroll
      for (int n = 0; n < 4; ++n) mfma_bf16(av[m], bv[n], acc[m][n]);
  }

  const float* b2e = b2 + (size_t)e * H_DIM;
#pragma unroll
  for (int m = 0; m < 4; ++m) {
    const int rw0 = wr * 64 + m * 16 + g * 4;
#pragma unroll
    for (int j = 0; j < 4; ++j) {
      const int p = tsp + rw0 + j;
      const int tok = pairTok[p];
      if (tok < 0) continue;
      const float pw = pairW[p];
      float* orow = out + (size_t)tok * H_DIM;
#pragma unroll
      for (int n = 0; n < 4; ++n) {
        const int col = n0 + wc * 64 + n * 16 + lrow;
        float val = (acc[m][n][j] + b2e[col]) * pw;
        atomicAdd(orow + col, val);
      }
    }
  }
}

// ------------------------------------------------------------------------------
extern "C" void kernel_launch(void* const* d_in, const int* in_sizes, int n_in,
                              void* d_out, int out_size, void* d_ws,
                              size_t ws_size, hipStream_t stream) {
  const float* x = (const float*)d_in[0];
  const float* rw = (const float*)d_in[1];
  const float* rb = (const float*)d_in[2];
  const float* w1 = (const float*)d_in[3];
  const float* b1 = (const float*)d_in[4];
  const float* w2 = (const float*)d_in[5];
  const float* b2 = (const float*)d_in[6];
  float* out = (float*)d_out;
  char* ws = (char*)d_ws;

  size_t off = 0;
  unsigned short* xb = (unsigned short*)(ws + off);
  off += (size_t)T_TOK * H_DIM * 2;
  unsigned short* wT = (unsigned short*)(ws + off);
  off += (size_t)E_NUM * H_DIM * I_DIM * 2;  // shared by w1T then w2T
  unsigned short* hmid = (unsigned short*)(ws + off);
  off += (size_t)PAD_PAIRS * I_DIM * 2;
  int* topi = (int*)(ws + off);      off += (size_t)T_TOK * K_TOP * 4;
  float* topw = (float*)(ws + off);  off += (size_t)T_TOK * K_TOP * 4;
  int* pairTok = (int*)(ws + off);   off += (size_t)PAD_PAIRS * 4;
  float* pairW = (float*)(ws + off); off += (size_t)PAD_PAIRS * 4;
  int* counts = (int*)(ws + off);    off += 64;
  int* cursor = (int*)(ws + off);    off += 64;
  int* padBase = (int*)(ws + off);   off += 64;
  int* tileExpert = (int*)(ws + off); off += MAX_TILES * 4;
  int* tileStart = (int*)(ws + off);  off += MAX_TILES * 4;
  int* nTiles = (int*)(ws + off);     off += 64;

  if (ws_size < off) return;  // diagnostic: output stays 0

  hipMemsetAsync(counts, 0, 64, stream);
  hipMemsetAsync(pairTok, 0xFF, (size_t)PAD_PAIRS * 4, stream);
  hipMemsetAsync(out, 0, (size_t)T_TOK * H_DIM * 4, stream);

  cvt_kernel<<<T_TOK * H_DIM / (256 * 8), 256, 0, stream>>>(x, xb);
  router_kernel<<<T_TOK / 16, 256, 0, stream>>>(x, rw, rb, topi, topw, counts);
  scan_kernel<<<1, 64, 0, stream>>>(counts, padBase, tileExpert, tileStart,
                                    nTiles, cursor);
  scatter_kernel<<<T_TOK / 256, 256, 0, stream>>>(topi, topw, padBase, cursor,
                                                  pairTok, pairW);
  transpose_kernel<<<dim3(I_DIM / 64, H_DIM / 64, E_NUM), 256, 0, stream>>>(
      w1, wT, H_DIM, I_DIM);
  gemm1_kernel<<<16 * MAX_TILES, 256, 0, stream>>>(
      xb, wT, b1, hmid, pairTok, tileExpert, tileStart, nTiles);
  transpose_kernel<<<dim3(H_DIM / 64, I_DIM / 64, E_NUM), 256, 0, stream>>>(
      w2, wT, I_DIM, H_DIM);
  gemm2_kernel<<<8 * MAX_TILES, 256, 0, stream>>>(
      hmid, wT, b2, out, pairTok, pairW, tileExpert, tileStart, nTiles);
}

// Round 3
// 492.189 us; speedup vs baseline: 1.3249x; 1.0046x over previous
//
#include <hip/hip_runtime.h>

#define T_TOK 4096
#define H_DIM 1024
#define I_DIM 2048
#define E_NUM 16
#define K_TOP 4
#define BM 128
#define BK 32
#define MAX_TILES 144
#define PAD_PAIRS (MAX_TILES * BM)  // 18432
#define RW_Q 4104                   // padded quarter stride (words) for router rw LDS

typedef __attribute__((ext_vector_type(8))) short s16x8;
typedef __attribute__((ext_vector_type(4))) float f32x4;
typedef __attribute__((ext_vector_type(4))) unsigned short u16x4;
typedef __attribute__((ext_vector_type(8))) unsigned short u16x8;

#define WAITV4 asm volatile("s_waitcnt vmcnt(4)" ::: "memory")
#define WAITV0 asm volatile("s_waitcnt vmcnt(0)" ::: "memory")

__device__ __forceinline__ unsigned short f2bf(float f) {
  unsigned u = __float_as_uint(f);
  u += 0x7fffu + ((u >> 16) & 1u);  // round-to-nearest-even
  return (unsigned short)(u >> 16);
}

__device__ __forceinline__ void mfma_bf16(const s16x8& a, const s16x8& b, f32x4& c) {
  asm("v_mfma_f32_16x16x32_bf16 %0, %1, %2, %0" : "+v"(c) : "v"(a), "v"(b));
}

__device__ __forceinline__ void gld16(const void* g, void* l) {
  __builtin_amdgcn_global_load_lds(
      (const __attribute__((address_space(1))) unsigned int*)g,
      (__attribute__((address_space(3))) unsigned int*)l, 16, 0, 0);
}

// ---------------- x -> bf16 (vectorized elementwise) --------------------------
__global__ __launch_bounds__(256) void cvt_kernel(const float* __restrict__ x,
                                                  unsigned short* __restrict__ xb) {
  size_t i = ((size_t)blockIdx.x * 256 + threadIdx.x) * 8;
  f32x4 a = *(const f32x4*)(x + i);
  f32x4 b = *(const f32x4*)(x + i + 4);
  u16x8 o;
  o[0] = f2bf(a[0]); o[1] = f2bf(a[1]); o[2] = f2bf(a[2]); o[3] = f2bf(a[3]);
  o[4] = f2bf(b[0]); o[5] = f2bf(b[1]); o[6] = f2bf(b[2]); o[7] = f2bf(b[3]);
  *(u16x8*)(xb + i) = o;
}

// ---------------- router: lane = (expert, quarter), rw in padded LDS ----------
__global__ __launch_bounds__(256) void router_kernel(
    const float* __restrict__ x, const float* __restrict__ rw,
    const float* __restrict__ rb, int* __restrict__ topi,
    float* __restrict__ topw, int* __restrict__ counts) {
  __shared__ float rws[4 * RW_Q];  // ~65.7 KB
  const int tid = threadIdx.x;
  for (int idx = tid * 4; idx < H_DIM * E_NUM; idx += 256 * 4) {
    f32x4 v = *(const f32x4*)(rw + idx);
    int h = idx >> 4, e0 = idx & 15;
    *(f32x4*)&rws[(h >> 8) * RW_Q + (h & 255) * 16 + e0] = v;
  }
  __syncthreads();
  const int w = tid >> 6, l = tid & 63;
  const int e = l & 15, q = l >> 4;
  const float rbe = rb[e];
  const float* ldsb = &rws[q * RW_Q + e];
#pragma unroll
  for (int i = 0; i < 4; ++i) {
    const int t = blockIdx.x * 16 + w * 4 + i;
    const float* xr = x + (size_t)t * H_DIM + (q << 8);
    float acc = 0.f;
#pragma unroll 8
    for (int hh = 0; hh < 256; hh += 4) {
      f32x4 xv = *(const f32x4*)(xr + hh);
      acc += xv[0] * ldsb[(hh + 0) * 16];
      acc += xv[1] * ldsb[(hh + 1) * 16];
      acc += xv[2] * ldsb[(hh + 2) * 16];
      acc += xv[3] * ldsb[(hh + 3) * 16];
    }
    acc += __shfl_xor(acc, 16);
    acc += __shfl_xor(acc, 32);
    float logit = acc + rbe;
    float m = logit;
    m = fmaxf(m, __shfl_xor(m, 1));
    m = fmaxf(m, __shfl_xor(m, 2));
    m = fmaxf(m, __shfl_xor(m, 4));
    m = fmaxf(m, __shfl_xor(m, 8));
    float ex = expf(logit - m);
    int rank = 0;
    const int b16 = l & 48;
#pragma unroll
    for (int j = 0; j < 16; ++j) {
      float vj = __shfl(ex, b16 + j);
      rank += (vj > ex) || (vj == ex && j < e);
    }
    float sel = (rank < K_TOP) ? ex : 0.f;
    float subs = sel;
    subs += __shfl_xor(subs, 1);
    subs += __shfl_xor(subs, 2);
    subs += __shfl_xor(subs, 4);
    subs += __shfl_xor(subs, 8);
    if (q == 0 && rank < K_TOP) {
      topi[t * K_TOP + rank] = e;
      topw[t * K_TOP + rank] = ex / subs;
      atomicAdd(&counts[e], 1);
    }
  }
}

// ---------------- scan: padded offsets + static tile map -----------------------
__global__ void scan_kernel(const int* __restrict__ counts, int* padBase,
                            int* tileExpert, int* tileStart, int* nTiles,
                            int* cursor) {
  if (threadIdx.x != 0 || blockIdx.x != 0) return;
  int base = 0, nt = 0;
  for (int e = 0; e < E_NUM; ++e) {
    padBase[e] = base;
    cursor[e] = 0;
    int tc = (counts[e] + BM - 1) >> 7;
    for (int i = 0; i < tc; ++i) {
      tileExpert[nt] = e;
      tileStart[nt] = base + (i << 7);
      ++nt;
    }
    base += tc << 7;
  }
  nTiles[0] = nt;
}

// ---------------- scatter pairs into per-expert sorted order ------------------
__global__ __launch_bounds__(256) void scatter_kernel(
    const int* __restrict__ topi, const float* __restrict__ topw,
    const int* __restrict__ padBase, int* __restrict__ cursor,
    int* __restrict__ pairTok, float* __restrict__ pairW) {
  int t = blockIdx.x * 256 + threadIdx.x;
  if (t >= T_TOK) return;
#pragma unroll
  for (int k = 0; k < K_TOP; ++k) {
    int e = topi[t * K_TOP + k];
    int pos = atomicAdd(&cursor[e], 1);
    int idx = padBase[e] + pos;
    pairTok[idx] = t;
    pairW[idx] = topw[t * K_TOP + k];
  }
}

// ---------------- transpose f32 [R][C] -> bf16 [C][R] per expert (z) ----------
__global__ __launch_bounds__(256) void transpose_kernel(
    const float* __restrict__ src, unsigned short* __restrict__ dst, int R,
    int C) {
  size_t es = (size_t)R * C;
  src += es * blockIdx.z;
  dst += es * blockIdx.z;
  int r0 = blockIdx.y * 64, c0 = blockIdx.x * 64;
  __shared__ float tle[64][65];
  int rr = threadIdx.x >> 4, cc = (threadIdx.x & 15) * 4;
#pragma unroll
  for (int i = 0; i < 4; ++i) {
    f32x4 v = *(const f32x4*)(src + (size_t)(r0 + rr + 16 * i) * C + c0 + cc);
    tle[rr + 16 * i][cc + 0] = v[0];
    tle[rr + 16 * i][cc + 1] = v[1];
    tle[rr + 16 * i][cc + 2] = v[2];
    tle[rr + 16 * i][cc + 3] = v[3];
  }
  __syncthreads();
#pragma unroll
  for (int i = 0; i < 4; ++i) {
    int oc = c0 + rr + 16 * i;
    u16x4 o;
    o[0] = f2bf(tle[cc + 0][rr + 16 * i]);
    o[1] = f2bf(tle[cc + 1][rr + 16 * i]);
    o[2] = f2bf(tle[cc + 2][rr + 16 * i]);
    o[3] = f2bf(tle[cc + 3][rr + 16 * i]);
    *(u16x4*)(dst + (size_t)oc * R + r0 + cc) = o;
  }
}

// ---------------- grouped GEMM1: hmid = gelu(x[pairs] @ w1 + b1) --------------
// 3-buffer pipeline, prefetch distance 2, counted vmcnt(4) across raw barriers.
// LDS XOR swizzle (verified r2: conflicts=0): stage chunk seg^((l>>3)&3),
// read chunk g^((l>>1)&3).
__global__ __launch_bounds__(256) void gemm1_kernel(
    const unsigned short* __restrict__ xb, const unsigned short* __restrict__ w1t,
    const float* __restrict__ b1, unsigned short* __restrict__ hmid,
    const int* __restrict__ pairTok, const int* __restrict__ tileExpert,
    const int* __restrict__ tileStart, const int* __restrict__ nTiles) {
  const int bid = blockIdx.x;
  const int lin = (bid & 7) * ((16 * MAX_TILES) >> 3) + (bid >> 3);  // XCD chunk
  const int tx = lin & 15, ty = lin >> 4;
  if (ty >= nTiles[0]) return;
  const int e = tileExpert[ty];
  const int tsp = tileStart[ty];
  const int n0 = tx * 128;
  __shared__ unsigned short As[3][BM * BK];
  __shared__ unsigned short Bs[3][BM * BK];
  const int tid = threadIdx.x, w = tid >> 6, l = tid & 63;
  const int rbase = w * 16 + (l >> 2);
  const int segp = (l & 3) ^ ((l >> 3) & 3);  // swizzled source chunk
  int tok0 = pairTok[tsp + rbase];
  if (tok0 < 0) tok0 = 0;
  int tok1 = pairTok[tsp + rbase + 64];
  if (tok1 < 0) tok1 = 0;
  const char* gA0 = (const char*)(xb + (size_t)tok0 * H_DIM) + segp * 16;
  const char* gA1 = (const char*)(xb + (size_t)tok1 * H_DIM) + segp * 16;
  const unsigned short* wbase = w1t + (size_t)e * I_DIM * H_DIM;
  const char* gB0 = (const char*)(wbase + (size_t)(n0 + rbase) * H_DIM) + segp * 16;
  const char* gB1 = (const char*)(wbase + (size_t)(n0 + rbase + 64) * H_DIM) + segp * 16;

  f32x4 acc[4][4];
#pragma unroll
  for (int m = 0; m < 4; ++m)
#pragma unroll
    for (int n = 0; n < 4; ++n) acc[m][n] = f32x4{0.f, 0.f, 0.f, 0.f};

  const int wr = w >> 1, wc = w & 1, lrow = l & 15, g = l >> 4;
  const int gs = g ^ ((l >> 1) & 3);  // swizzled read chunk
  const int NK = H_DIM / BK;  // 32

  auto STAGE = [&](int kt, int b) {
    const int kb = kt * 64;  // BK*2 bytes
    gld16(gA0 + kb, &As[b][w * 512]);
    gld16(gA1 + kb, &As[b][2048 + w * 512]);
    gld16(gB0 + kb, &Bs[b][w * 512]);
    gld16(gB1 + kb, &Bs[b][2048 + w * 512]);
  };
  auto COMPUTE = [&](int b) {
    const s16x8* Ap = (const s16x8*)As[b];
    const s16x8* Bp = (const s16x8*)Bs[b];
    s16x8 av[4], bv[4];
#pragma unroll
    for (int m = 0; m < 4; ++m) av[m] = Ap[(wr * 64 + m * 16 + lrow) * 4 + gs];
#pragma unroll
    for (int n = 0; n < 4; ++n) bv[n] = Bp[(wc * 64 + n * 16 + lrow) * 4 + gs];
    __builtin_amdgcn_s_setprio(1);
#pragma unroll
    for (int m = 0; m < 4; ++m)
#pragma unroll
      for (int n = 0; n < 4; ++n) mfma_bf16(av[m], bv[n], acc[m][n]);
    __builtin_amdgcn_s_setprio(0);
  };

  STAGE(0, 0);
  STAGE(1, 1);
  int cb = 0, sb = 2;
  for (int kt = 0; kt < NK - 1; ++kt) {
    WAITV4;                         // my tile-kt loads done; tile-(kt+1) in flight
    __builtin_amdgcn_s_barrier();   // everyone's tile-kt loads done
    if (kt + 2 < NK) STAGE(kt + 2, sb);
    COMPUTE(cb);
    cb = (cb == 2) ? 0 : cb + 1;
    sb = (sb == 2) ? 0 : sb + 1;
  }
  WAITV0;
  __builtin_amdgcn_s_barrier();
  COMPUTE(cb);

  const float* b1e = b1 + (size_t)e * I_DIM;
#pragma unroll
  for (int m = 0; m < 4; ++m) {
    const int rw0 = wr * 64 + m * 16 + g * 4;
#pragma unroll
    for (int n = 0; n < 4; ++n) {
      const int col = n0 + wc * 64 + n * 16 + lrow;
      const float bb = b1e[col];
      f32x4 v = acc[m][n];
#pragma unroll
      for (int j = 0; j < 4; ++j) {
        const int p = tsp + rw0 + j;
        float xv = v[j] + bb;
        float ge = 0.5f * xv * (1.f + erff(xv * 0.7071067811865476f));
        hmid[(size_t)p * I_DIM + col] = f2bf(ge);
      }
    }
  }
}

// ---------------- grouped GEMM2: out += ((hmid @ w2) + b2) * pairW ------------
__global__ __launch_bounds__(256) void gemm2_kernel(
    const unsigned short* __restrict__ hmid,
    const unsigned short* __restrict__ w2t, const float* __restrict__ b2,
    float* __restrict__ out, const int* __restrict__ pairTok,
    const float* __restrict__ pairW, const int* __restrict__ tileExpert,
    const int* __restrict__ tileStart, const int* __restrict__ nTiles) {
  const int bid = blockIdx.x;
  const int lin = (bid & 7) * ((8 * MAX_TILES) >> 3) + (bid >> 3);  // XCD chunk
  const int tx = lin & 7, ty = lin >> 3;
  if (ty >= nTiles[0]) return;
  const int e = tileExpert[ty];
  const int tsp = tileStart[ty];
  const int n0 = tx * 128;
  __shared__ unsigned short As[3][BM * BK];
  __shared__ unsigned short Bs[3][BM * BK];
  const int tid = threadIdx.x, w = tid >> 6, l = tid & 63;
  const int rbase = w * 16 + (l >> 2);
  const int segp = (l & 3) ^ ((l >> 3) & 3);
  const char* gA0 = (const char*)(hmid + (size_t)(tsp + rbase) * I_DIM) + segp * 16;
  const char* gA1 = (const char*)(hmid + (size_t)(tsp + rbase + 64) * I_DIM) + segp * 16;
  const unsigned short* wbase = w2t + (size_t)e * H_DIM * I_DIM;
  const char* gB0 = (const char*)(wbase + (size_t)(n0 + rbase) * I_DIM) + segp * 16;
  const char* gB1 = (const char*)(wbase + (size_t)(n0 + rbase + 64) * I_DIM) + segp * 16;

  f32x4 acc[4][4];
#pragma unroll
  for (int m = 0; m < 4; ++m)
#pragma unroll
    for (int n = 0; n < 4; ++n) acc[m][n] = f32x4{0.f, 0.f, 0.f, 0.f};

  const int wr = w >> 1, wc = w & 1, lrow = l & 15, g = l >> 4;
  const int gs = g ^ ((l >> 1) & 3);
  const int NK = I_DIM / BK;  // 64

  auto STAGE = [&](int kt, int b) {
    const int kb = kt * 64;
    gld16(gA0 + kb, &As[b][w * 512]);
    gld16(gA1 + kb, &As[b][2048 + w * 512]);
    gld16(gB0 + kb, &Bs[b][w * 512]);
    gld16(gB1 + kb, &Bs[b][2048 + w * 512]);
  };
  auto COMPUTE = [&](int b) {
    const s16x8* Ap = (const s16x8*)As[b];
    const s16x8* Bp = (const s16x8*)Bs[b];
    s16x8 av[4], bv[4];
#pragma unroll
    for (int m = 0; m < 4; ++m) av[m] = Ap[(wr * 64 + m * 16 + lrow) * 4 + gs];
#pragma unroll
    for (int n = 0; n < 4; ++n) bv[n] = Bp[(wc * 64 + n * 16 + lrow) * 4 + gs];
    __builtin_amdgcn_s_setprio(1);
#pragma unroll
    for (int m = 0; m < 4; ++m)
#pragma unroll
      for (int n = 0; n < 4; ++n) mfma_bf16(av[m], bv[n], acc[m][n]);
    __builtin_amdgcn_s_setprio(0);
  };

  STAGE(0, 0);
  STAGE(1, 1);
  int cb = 0, sb = 2;
  for (int kt = 0; kt < NK - 1; ++kt) {
    WAITV4;
    __builtin_amdgcn_s_barrier();
    if (kt + 2 < NK) STAGE(kt + 2, sb);
    COMPUTE(cb);
    cb = (cb == 2) ? 0 : cb + 1;
    sb = (sb == 2) ? 0 : sb + 1;
  }
  WAITV0;
  __builtin_amdgcn_s_barrier();
  COMPUTE(cb);

  const float* b2e = b2 + (size_t)e * H_DIM;
#pragma unroll
  for (int m = 0; m < 4; ++m) {
    const int rw0 = wr * 64 + m * 16 + g * 4;
#pragma unroll
    for (int j = 0; j < 4; ++j) {
      const int p = tsp + rw0 + j;
      const int tok = pairTok[p];
      if (tok < 0) continue;
      const float pw = pairW[p];
      float* orow = out + (size_t)tok * H_DIM;
#pragma unroll
      for (int n = 0; n < 4; ++n) {
        const int col = n0 + wc * 64 + n * 16 + lrow;
        float val = (acc[m][n][j] + b2e[col]) * pw;
        atomicAdd(orow + col, val);
      }
    }
  }
}

// ------------------------------------------------------------------------------
extern "C" void kernel_launch(void* const* d_in, const int* in_sizes, int n_in,
                              void* d_out, int out_size, void* d_ws,
                              size_t ws_size, hipStream_t stream) {
  const float* x = (const float*)d_in[0];
  const float* rw = (const float*)d_in[1];
  const float* rb = (const float*)d_in[2];
  const float* w1 = (const float*)d_in[3];
  const float* b1 = (const float*)d_in[4];
  const float* w2 = (const float*)d_in[5];
  const float* b2 = (const float*)d_in[6];
  float* out = (float*)d_out;
  char* ws = (char*)d_ws;

  size_t off = 0;
  unsigned short* xb = (unsigned short*)(ws + off);
  off += (size_t)T_TOK * H_DIM * 2;
  unsigned short* wT = (unsigned short*)(ws + off);
  off += (size_t)E_NUM * H_DIM * I_DIM * 2;  // shared by w1T then w2T
  unsigned short* hmid = (unsigned short*)(ws + off);
  off += (size_t)PAD_PAIRS * I_DIM * 2;
  int* topi = (int*)(ws + off);      off += (size_t)T_TOK * K_TOP * 4;
  float* topw = (float*)(ws + off);  off += (size_t)T_TOK * K_TOP * 4;
  int* pairTok = (int*)(ws + off);   off += (size_t)PAD_PAIRS * 4;
  float* pairW = (float*)(ws + off); off += (size_t)PAD_PAIRS * 4;
  int* counts = (int*)(ws + off);    off += 64;
  int* cursor = (int*)(ws + off);    off += 64;
  int* padBase = (int*)(ws + off);   off += 64;
  int* tileExpert = (int*)(ws + off); off += MAX_TILES * 4;
  int* tileStart = (int*)(ws + off);  off += MAX_TILES * 4;
  int* nTiles = (int*)(ws + off);     off += 64;

  if (ws_size < off) return;  // diagnostic: output stays 0

  hipMemsetAsync(counts, 0, 64, stream);
  hipMemsetAsync(pairTok, 0xFF, (size_t)PAD_PAIRS * 4, stream);
  hipMemsetAsync(out, 0, (size_t)T_TOK * H_DIM * 4, stream);

  cvt_kernel<<<T_TOK * H_DIM / (256 * 8), 256, 0, stream>>>(x, xb);
  router_kernel<<<T_TOK / 16, 256, 0, stream>>>(x, rw, rb, topi, topw, counts);
  scan_kernel<<<1, 64, 0, stream>>>(counts, padBase, tileExpert, tileStart,
                                    nTiles, cursor);
  scatter_kernel<<<T_TOK / 256, 256, 0, stream>>>(topi, topw, padBase, cursor,
                                                  pairTok, pairW);
  transpose_kernel<<<dim3(I_DIM / 64, H_DIM / 64, E_NUM), 256, 0, stream>>>(
      w1, wT, H_DIM, I_DIM);
  gemm1_kernel<<<16 * MAX_TILES, 256, 0, stream>>>(
      xb, wT, b1, hmid, pairTok, tileExpert, tileStart, nTiles);
  transpose_kernel<<<dim3(H_DIM / 64, I_DIM / 64, E_NUM), 256, 0, stream>>>(
      w2, wT, I_DIM, H_DIM);
  gemm2_kernel<<<8 * MAX_TILES, 256, 0, stream>>>(
      hmid, wT, b2, out, pairTok, pairW, tileExpert, tileStart, nTiles);
}